// Round 4
// baseline (283.244 us; speedup 1.0000x reference)
//
#include <hip/hip_runtime.h>
#include <hip/hip_bf16.h>

typedef __attribute__((ext_vector_type(4))) float f32x4;
typedef __attribute__((ext_vector_type(8))) short bf16x8;

#define NPART 8192
#define DDIM 64
#define PDIM 32
#define MSTEPS 50
#define HDIM 512
#define MB 16      // particles per block
#define A_LD 72    // shorts
#define H_LD 520   // shorts

__device__ __forceinline__ short f2bf(float f) {
  unsigned u = __builtin_bit_cast(unsigned, f);
  u = (u + 0x7fffu + ((u >> 16) & 1u)) >> 16;
  return (short)u;
}

__device__ __forceinline__ float fast_tanh(float xv) {
  float t = __expf(2.0f * xv);
  return 1.0f - 2.0f * __builtin_amdgcn_rcpf(t + 1.0f);
}

// lane-pair (c, c+1) pack: even lane returns bf16(own)|bf16(neighbor)<<16
__device__ __forceinline__ unsigned pack_pair(float own) {
  int oi = __builtin_amdgcn_mov_dpp(__builtin_bit_cast(int, own),
                                    0xB1 /*quad_perm(1,0,3,2)*/, 0xF, 0xF, true);
  float other = __builtin_bit_cast(float, oi);
  unsigned out;
  asm("v_cvt_pk_bf16_f32 %0, %1, %2" : "=v"(out) : "v"(own), "v"(other));
  return out;  // valid on even lanes
}

// 512 threads = 8 waves, 16 particles/block, grid 512 -> 2 blocks/CU.
// GEMM1 (h = [X]@W1x, K=64): wave w owns h-cols [64w, 64w+64) as 4 16-col tiles.
// GEMM2 (Z = h@W2, K=512): role (ntw = w&3, kh = w>>2); kh = K-half owner;
//   kh1 ships partial via lds_p to kh0, which holds X state and does updates.
__global__ __launch_bounds__(512, 4) void sde_kernel(
    const float* __restrict__ X0, const float* __restrict__ V0,
    const float* __restrict__ Y, const float* __restrict__ theta,
    const float* __restrict__ W1, const float* __restrict__ b1,
    const float* __restrict__ W2, const float* __restrict__ b2,
    const float* __restrict__ noise, const int* __restrict__ obs_index,
    float* __restrict__ out) {
  __shared__ __align__(16) short lds_h[MB * H_LD];  // 16.6 KB
  __shared__ __align__(16) short lds_a[MB * A_LD];  // 2.3 KB
  __shared__ __align__(16) float lds_p[4 * 64 * 4]; // 4 KB: Yt scratch / Z-partials / V-final

  const int tid = threadIdx.x;
  const int w = tid >> 6;
  const int lane = tid & 63;
  const int c = lane & 15;
  const int g = lane >> 4;
  const int pb = blockIdx.x * MB;
  const int ntw = w & 3, kh = w >> 2;

  const float dt = 0.02f;
  const float sqdt = sqrtf(dt);

  // ---- stage Yt (f32): one element per thread ----
  {
    int m = tid >> 5, p = tid & 31;
    lds_p[tid] = Y[(size_t)(pb + m) * PDIM + (size_t)obs_index[0] * PDIM + p];
  }

  // ---- X state (kh0 waves, GEMM2-D layout) + initial A-tile ----
  float x[4] = {0.f, 0.f, 0.f, 0.f};
  if (kh == 0) {
    #pragma unroll
    for (int r = 0; r < 4; ++r) {
      int m = 4 * g + r;
      x[r] = X0[(size_t)(pb + m) * DDIM + 16 * ntw + c];
      lds_a[m * A_LD + 16 * ntw + c] = f2bf(x[r]);
    }
  }
  __syncthreads();

  // ---- cy[j] = (Yt @ W1[65:97] + b1) in GEMM1-acc layout (f32x4 per n-tile) ----
  const int nj0 = 64 * w + c;
  f32x4 cy[4];
  float rv0[4];
  #pragma unroll
  for (int j = 0; j < 4; ++j) {
    rv0[j] = W1[nj0 + 16 * j];
    float bv = b1[nj0 + 16 * j];
    cy[j] = (f32x4){bv, bv, bv, bv};
  }
  for (int p = 0; p < PDIM; ++p) {
    float yv[4];
    #pragma unroll
    for (int r = 0; r < 4; ++r) yv[r] = lds_p[(4 * g + r) * PDIM + p];
    #pragma unroll
    for (int j = 0; j < 4; ++j) {
      float wv = W1[(size_t)(65 + p) * HDIM + nj0 + 16 * j];
      #pragma unroll
      for (int r = 0; r < 4; ++r) cy[j][r] = fmaf(yv[r], wv, cy[j][r]);
    }
  }

  // ---- W1 X-part B-fragments in registers (loop-invariant) ----
  bf16x8 bfr[4][2];
  #pragma unroll
  for (int j = 0; j < 4; ++j)
    #pragma unroll
    for (int kt = 0; kt < 2; ++kt)
      #pragma unroll
      for (int i = 0; i < 8; ++i)
        bfr[j][kt][i] =
            f2bf(W1[(size_t)(1 + 32 * kt + 8 * g + i) * HDIM + nj0 + 16 * j]);

  // ---- W2 B-fragments (this wave's K-half, 16-col slice) ----
  bf16x8 w2f[8];
  #pragma unroll
  for (int kt = 0; kt < 8; ++kt)
    #pragma unroll
    for (int i = 0; i < 8; ++i)
      w2f[kt][i] =
          f2bf(W2[(size_t)(256 * kh + 32 * kt + 8 * g + i) * DDIM + 16 * ntw + c]);

  const float thv = theta[16 * ntw + c];
  const float b2v = b2[16 * ntw + c];
  float vacc[4] = {0.f, 0.f, 0.f, 0.f};

  __syncthreads();  // Yt scratch free; A-tile ready

  for (int st = 0; st < MSTEPS; ++st) {
    const float s = st * dt;

    // prefetch this step's noise (kh0 only; consumed after GEMM2)
    float wm[4];
    if (kh == 0) {
      const float* np_ =
          noise + ((size_t)st * NPART + pb + 4 * g) * DDIM + 16 * ntw + c;
      #pragma unroll
      for (int r = 0; r < 4; ++r) wm[r] = np_[(size_t)r * DDIM];
    }

    // ---- GEMM1 + tanh epilogue -> lds_h ----
    {
      const int abase = c * A_LD + 8 * g;
      bf16x8 af0 = *reinterpret_cast<const bf16x8*>(&lds_a[abase]);
      bf16x8 af1 = *reinterpret_cast<const bf16x8*>(&lds_a[abase + 32]);
      #pragma unroll
      for (int j = 0; j < 4; ++j) {
        f32x4 acc = cy[j];
        acc = __builtin_amdgcn_mfma_f32_16x16x32_bf16(af0, bfr[j][0], acc, 0, 0, 0);
        acc = __builtin_amdgcn_mfma_f32_16x16x32_bf16(af1, bfr[j][1], acc, 0, 0, 0);
        unsigned pk[4];
        #pragma unroll
        for (int r = 0; r < 4; ++r)
          pk[r] = pack_pair(fast_tanh(fmaf(s, rv0[j], acc[r])));
        if (!(lane & 1)) {
          #pragma unroll
          for (int r = 0; r < 4; ++r)
            *reinterpret_cast<unsigned*>(
                &lds_h[(4 * g + r) * H_LD + nj0 + 16 * j]) = pk[r];
        }
      }
    }

    __syncthreads();  // B1: h ready

    // ---- GEMM2 K-half ----
    f32x4 acc2 = kh ? (f32x4){0.f, 0.f, 0.f, 0.f} : (f32x4){b2v, b2v, b2v, b2v};
    {
      const int hbase = c * H_LD + 256 * kh + 8 * g;
      #pragma unroll
      for (int kt = 0; kt < 8; ++kt)
        acc2 = __builtin_amdgcn_mfma_f32_16x16x32_bf16(
            *reinterpret_cast<const bf16x8*>(&lds_h[hbase + 32 * kt]), w2f[kt],
            acc2, 0, 0, 0);
    }
    float* pslot = &lds_p[(ntw * 64 + lane) * 4];
    if (kh) *reinterpret_cast<f32x4*>(pslot) = acc2;

    __syncthreads();  // B2: partials ready

    if (!kh) {
      f32x4 part = *reinterpret_cast<const f32x4*>(pslot);
      unsigned apk[4];
      #pragma unroll
      for (int r = 0; r < 4; ++r) {
        float z = acc2[r] + part[r];
        float wmr = sqdt * wm[r];
        vacc[r] = fmaf(z, fmaf(-0.5f * dt, z, wmr), vacc[r]);
        x[r] = fmaf(dt, thv - x[r] - z, x[r]) + wmr;
        apk[r] = pack_pair(x[r]);
      }
      if (!(lane & 1)) {
        #pragma unroll
        for (int r = 0; r < 4; ++r)
          *reinterpret_cast<unsigned*>(
              &lds_a[(4 * g + r) * A_LD + 16 * ntw + c]) = apk[r];
      }
    }

    __syncthreads();  // B3: A-tile ready for next step
  }

  // ---- output: X (N x 64 f32), then V (N f32) ----
  if (!kh) {
    #pragma unroll
    for (int r = 0; r < 4; ++r)
      out[(size_t)(pb + 4 * g + r) * DDIM + 16 * ntw + c] = x[r];
    #pragma unroll
    for (int mask = 1; mask <= 8; mask <<= 1)
      #pragma unroll
      for (int r = 0; r < 4; ++r) vacc[r] += __shfl_xor(vacc[r], mask);
    if (c == 0) {
      #pragma unroll
      for (int r = 0; r < 4; ++r)
        lds_p[(4 * g + r) * 4 + ntw] = vacc[r];
    }
  }
  __syncthreads();
  if (tid < MB)
    out[(size_t)NPART * DDIM + pb + tid] =
        V0[pb + tid] + lds_p[tid * 4] + lds_p[tid * 4 + 1] +
        lds_p[tid * 4 + 2] + lds_p[tid * 4 + 3];
}

extern "C" void kernel_launch(void* const* d_in, const int* in_sizes, int n_in,
                              void* d_out, int out_size, void* d_ws, size_t ws_size,
                              hipStream_t stream) {
  sde_kernel<<<512, 512, 0, stream>>>(
      (const float*)d_in[0], (const float*)d_in[1], (const float*)d_in[2],
      (const float*)d_in[3], (const float*)d_in[4], (const float*)d_in[5],
      (const float*)d_in[6], (const float*)d_in[7], (const float*)d_in[8],
      (const int*)d_in[9], (float*)d_out);
}

// Round 5
// 271.701 us; speedup vs baseline: 1.0425x; 1.0425x over previous
//
#include <hip/hip_runtime.h>
#include <hip/hip_fp16.h>

typedef __attribute__((ext_vector_type(4))) float f32x4;
typedef __attribute__((ext_vector_type(8))) _Float16 f16x8;

#define NPART 8192
#define DDIM 64
#define PDIM 32
#define MSTEPS 50
#define HDIM 512
#define MB 16      // particles per block
#define A_LD 72    // f16 elems
#define H_LD 520   // f16 elems

// lane-pair (c, c+1) pack: even lane returns f16(own)|f16(neighbor)<<16
__device__ __forceinline__ unsigned pack_pair(float own) {
  int oi = __builtin_amdgcn_mov_dpp(__builtin_bit_cast(int, own),
                                    0xB1 /*quad_perm(1,0,3,2)*/, 0xF, 0xF, true);
  float other = __builtin_bit_cast(float, oi);
  unsigned out;
  asm("v_cvt_pkrtz_f16_f32 %0, %1, %2" : "=v"(out) : "v"(own), "v"(other));
  return out;  // valid on even lanes
}

// 512 threads = 8 waves, 16 particles/block, grid 512 -> 2 blocks/CU.
// GEMM1 (h = [X]@W1x, K=64): wave w owns h-cols [64w, 64w+64) as 4 16-col tiles.
// GEMM2 (Z = h@W2, K=512): role (ntw = w&3, kh = w>>2); both K-halves exchange
//   partials; kh1 owns X-state/update/A-write, kh0 owns V-accumulation.
__global__ __launch_bounds__(512, 4) void sde_kernel(
    const float* __restrict__ X0, const float* __restrict__ V0,
    const float* __restrict__ Y, const float* __restrict__ theta,
    const float* __restrict__ W1, const float* __restrict__ b1,
    const float* __restrict__ W2, const float* __restrict__ b2,
    const float* __restrict__ noise, const int* __restrict__ obs_index,
    float* __restrict__ out) {
  __shared__ __align__(16) _Float16 lds_h[MB * H_LD];  // 16.6 KB
  __shared__ __align__(16) _Float16 lds_a[MB * A_LD];  // 2.3 KB
  __shared__ __align__(16) float lds_p[2048];          // 8 KB: Yt / Z-partials / V-final

  const int tid = threadIdx.x;
  const int w = tid >> 6;
  const int lane = tid & 63;
  const int c = lane & 15;
  const int g = lane >> 4;
  const int pb = blockIdx.x * MB;
  const int ntw = w & 3, kh = w >> 2;

  const float dt = 0.02f;
  const float sqdt = sqrtf(dt);

  // ---- stage Yt (f32): one element per thread ----
  lds_p[tid] = Y[(size_t)(pb + (tid >> 5)) * PDIM + (size_t)obs_index[0] * PDIM +
                 (tid & 31)];

  // ---- X state (kh1 waves, GEMM2-D layout) + initial A-tile ----
  float x[4] = {0.f, 0.f, 0.f, 0.f};
  if (kh) {
    #pragma unroll
    for (int r = 0; r < 4; ++r) {
      int m = 4 * g + r;
      x[r] = X0[(size_t)(pb + m) * DDIM + 16 * ntw + c];
      lds_a[m * A_LD + 16 * ntw + c] = (_Float16)x[r];
    }
  }
  __syncthreads();

  // ---- cy2[j] = 2*(Yt @ W1[65:97] + b1); rv02 = 2*W1[0] (prescaled for exp) ----
  const int nj0 = 64 * w + c;
  f32x4 cy2[4];
  float rv02[4];
  #pragma unroll
  for (int j = 0; j < 4; ++j) {
    rv02[j] = 2.0f * W1[nj0 + 16 * j];
    float bv = b1[nj0 + 16 * j];
    cy2[j] = (f32x4){bv, bv, bv, bv};
  }
  for (int p = 0; p < PDIM; ++p) {
    float yv[4];
    #pragma unroll
    for (int r = 0; r < 4; ++r) yv[r] = lds_p[(4 * g + r) * PDIM + p];
    #pragma unroll
    for (int j = 0; j < 4; ++j) {
      float wv = W1[(size_t)(65 + p) * HDIM + nj0 + 16 * j];
      #pragma unroll
      for (int r = 0; r < 4; ++r) cy2[j][r] = fmaf(yv[r], wv, cy2[j][r]);
    }
  }
  #pragma unroll
  for (int j = 0; j < 4; ++j)
    #pragma unroll
    for (int r = 0; r < 4; ++r) cy2[j][r] *= 2.0f;

  // ---- W1 X-part B-fragments in registers (loop-invariant) ----
  f16x8 bfr[4][2];
  #pragma unroll
  for (int j = 0; j < 4; ++j)
    #pragma unroll
    for (int kt = 0; kt < 2; ++kt)
      #pragma unroll
      for (int i = 0; i < 8; ++i)
        bfr[j][kt][i] =
            (_Float16)W1[(size_t)(1 + 32 * kt + 8 * g + i) * HDIM + nj0 + 16 * j];

  // ---- W2 B-fragments (this wave's K-half, 16-col slice) ----
  f16x8 w2f[8];
  #pragma unroll
  for (int kt = 0; kt < 8; ++kt)
    #pragma unroll
    for (int i = 0; i < 8; ++i)
      w2f[kt][i] =
          (_Float16)W2[(size_t)(256 * kh + 32 * kt + 8 * g + i) * DDIM + 16 * ntw + c];

  const float thv = theta[16 * ntw + c];
  const float b2v = b2[16 * ntw + c];
  float vacc[4] = {0.f, 0.f, 0.f, 0.f};

  const float* np_ = noise + ((size_t)pb + 4 * g) * DDIM + 16 * ntw + c;

  for (int st = 0; st < MSTEPS; ++st) {
    const float s = st * dt;

    // noise prefetch (all waves; consumed after GEMM2)
    float wm[4];
    #pragma unroll
    for (int r = 0; r < 4; ++r) wm[r] = np_[(size_t)r * DDIM];
    np_ += (size_t)NPART * DDIM;

    // hoisted exp-arg constants (off the MFMA-dependent path)
    float csr[4][4];
    #pragma unroll
    for (int j = 0; j < 4; ++j)
      #pragma unroll
      for (int r = 0; r < 4; ++r) csr[j][r] = fmaf(s, rv02[j], cy2[j][r]);

    // ---- GEMM1 + tanh epilogue -> lds_h ----
    {
      const int abase = c * A_LD + 8 * g;
      f16x8 af0 = *reinterpret_cast<const f16x8*>(&lds_a[abase]);
      f16x8 af1 = *reinterpret_cast<const f16x8*>(&lds_a[abase + 32]);
      #pragma unroll
      for (int j = 0; j < 4; ++j) {
        f32x4 acc = (f32x4){0.f, 0.f, 0.f, 0.f};
        acc = __builtin_amdgcn_mfma_f32_16x16x32_f16(af0, bfr[j][0], acc, 0, 0, 0);
        acc = __builtin_amdgcn_mfma_f32_16x16x32_f16(af1, bfr[j][1], acc, 0, 0, 0);
        unsigned pk[4];
        #pragma unroll
        for (int r = 0; r < 4; ++r) {
          // tanh(v) = 1 - 2/(1+e^{2v}); e^{2v} = __expf(2*acc + csr)
          float e = __expf(fmaf(2.0f, acc[r], csr[j][r]));
          float th = fmaf(-2.0f, __builtin_amdgcn_rcpf(e + 1.0f), 1.0f);
          pk[r] = pack_pair(th);
        }
        if (!(lane & 1)) {
          #pragma unroll
          for (int r = 0; r < 4; ++r)
            *reinterpret_cast<unsigned*>(
                &lds_h[(4 * g + r) * H_LD + nj0 + 16 * j]) = pk[r];
        }
      }
    }

    __syncthreads();  // B1: h ready

    // ---- GEMM2 K-half (two independent MFMA chains) ----
    f32x4 a2a = kh ? (f32x4){0.f, 0.f, 0.f, 0.f} : (f32x4){b2v, b2v, b2v, b2v};
    f32x4 a2b = (f32x4){0.f, 0.f, 0.f, 0.f};
    {
      const int hbase = c * H_LD + 256 * kh + 8 * g;
      #pragma unroll
      for (int kt = 0; kt < 4; ++kt) {
        a2a = __builtin_amdgcn_mfma_f32_16x16x32_f16(
            *reinterpret_cast<const f16x8*>(&lds_h[hbase + 64 * kt]), w2f[2 * kt],
            a2a, 0, 0, 0);
        a2b = __builtin_amdgcn_mfma_f32_16x16x32_f16(
            *reinterpret_cast<const f16x8*>(&lds_h[hbase + 64 * kt + 32]),
            w2f[2 * kt + 1], a2b, 0, 0, 0);
      }
    }
    f32x4 acc2;
    #pragma unroll
    for (int r = 0; r < 4; ++r) acc2[r] = a2a[r] + a2b[r];

    // both halves publish partials
    *reinterpret_cast<f32x4*>(&lds_p[(kh * 256 + ntw * 64 + lane) * 4]) = acc2;

    __syncthreads();  // B2: partials ready

    {
      f32x4 oth = *reinterpret_cast<const f32x4*>(
          &lds_p[((1 - kh) * 256 + ntw * 64 + lane) * 4]);
      if (kh) {
        // X-update + A-write
        unsigned apk[4];
        #pragma unroll
        for (int r = 0; r < 4; ++r) {
          float z = acc2[r] + oth[r];
          float wmr = sqdt * wm[r];
          x[r] = fmaf(dt, thv - x[r] - z, x[r]) + wmr;
          apk[r] = pack_pair(x[r]);
        }
        if (!(lane & 1)) {
          #pragma unroll
          for (int r = 0; r < 4; ++r)
            *reinterpret_cast<unsigned*>(
                &lds_a[(4 * g + r) * A_LD + 16 * ntw + c]) = apk[r];
        }
      } else {
        // V-accumulation
        #pragma unroll
        for (int r = 0; r < 4; ++r) {
          float z = acc2[r] + oth[r];
          float wmr = sqdt * wm[r];
          vacc[r] = fmaf(z, fmaf(-0.5f * dt, z, wmr), vacc[r]);
        }
      }
    }

    __syncthreads();  // B3: A-tile ready for next step
  }

  // ---- output: X (N x 64 f32) from kh1, V (N f32) from kh0 ----
  if (kh) {
    #pragma unroll
    for (int r = 0; r < 4; ++r)
      out[(size_t)(pb + 4 * g + r) * DDIM + 16 * ntw + c] = x[r];
  } else {
    #pragma unroll
    for (int mask = 1; mask <= 8; mask <<= 1)
      #pragma unroll
      for (int r = 0; r < 4; ++r) vacc[r] += __shfl_xor(vacc[r], mask);
    if (c == 0) {
      #pragma unroll
      for (int r = 0; r < 4; ++r)
        lds_p[(4 * g + r) * 4 + ntw] = vacc[r];
    }
  }
  __syncthreads();
  if (tid < MB)
    out[(size_t)NPART * DDIM + pb + tid] =
        V0[pb + tid] + lds_p[tid * 4] + lds_p[tid * 4 + 1] +
        lds_p[tid * 4 + 2] + lds_p[tid * 4 + 3];
}

extern "C" void kernel_launch(void* const* d_in, const int* in_sizes, int n_in,
                              void* d_out, int out_size, void* d_ws, size_t ws_size,
                              hipStream_t stream) {
  sde_kernel<<<512, 512, 0, stream>>>(
      (const float*)d_in[0], (const float*)d_in[1], (const float*)d_in[2],
      (const float*)d_in[3], (const float*)d_in[4], (const float*)d_in[5],
      (const float*)d_in[6], (const float*)d_in[7], (const float*)d_in[8],
      (const int*)d_in[9], (float*)d_out);
}